// Round 1
// baseline (909.574 us; speedup 1.0000x reference)
//
#include <hip/hip_runtime.h>
#include <cmath>

constexpr int NB   = 32768;   // batch rows
constexpr int IND  = 512;
constexpr int HIDD = 64;
constexpr int CM   = 128;     // COMM
constexpr int NP   = 2048;    // num protos
constexpr float BETA  = 0.25f;
constexpr float ENT_W = 0.1f;
constexpr float EPSV  = 1e-8f;

__device__ __forceinline__ float4 ld4(const float* p){ return *reinterpret_cast<const float4*>(p); }
__device__ __forceinline__ void  st4(float* p, float4 v){ *reinterpret_cast<float4*>(p) = v; }

__device__ __forceinline__ float wave_sum(float v){
  #pragma unroll
  for (int m = 1; m < 64; m <<= 1) v += __shfl_xor(v, m, 64);
  return v;
}

// ---------------- K0: per-proto squared norms ----------------
__global__ __launch_bounds__(256) void k_normp2(const float* __restrict__ protos,
                                                float* __restrict__ normp2){
  int p = blockIdx.x * 256 + threadIdx.x;
  const float* row = protos + (size_t)p * CM;
  float s = 0.f;
  #pragma unroll
  for (int k = 0; k < CM; k += 4){
    float4 v = ld4(row + k);
    s += v.x*v.x + v.y*v.y + v.z*v.z + v.w*v.w;
  }
  normp2[p] = s;
}

// ---------------- MLP tiled GEMM (fp32): Out = act(A@W + b) ----------------
template<int K, int N, bool RELU>
__global__ __launch_bounds__(256) void mlp_gemm(const float* __restrict__ A,
                                                const float* __restrict__ W,
                                                const float* __restrict__ bias,
                                                float* __restrict__ Out){
  constexpr int BM = 128, KC = 32;
  constexpr int TN = N / 16;        // 4 or 8
  constexpr int NFRAG = TN / 4;     // 1 or 2 (frags at cg*4 and cg*4+64)
  __shared__ float At[KC][BM + 4];  // transposed A tile
  __shared__ float Wl[KC][N];
  const int tid = threadIdx.x;
  const int r0 = (tid >> 4) * 8;
  const int cg = tid & 15;
  const int arow = tid >> 3, kq = tid & 7;
  const int cq = tid % (N / 4), kr = tid / (N / 4);
  constexpr int KRS = 256 / (N / 4);
  constexpr int WI  = (KC * N) / 1024;
  const int rowbase = blockIdx.x * BM;

  float acc[8][TN];
  #pragma unroll
  for (int i = 0; i < 8; i++)
    #pragma unroll
    for (int j = 0; j < TN; j++) acc[i][j] = 0.f;

  for (int kc = 0; kc < K; kc += KC){
    #pragma unroll
    for (int i = 0; i < 4; i++){
      float4 v = ld4(A + (size_t)(rowbase + arow + i*32) * K + kc + kq*4);
      At[kq*4+0][arow + i*32] = v.x;
      At[kq*4+1][arow + i*32] = v.y;
      At[kq*4+2][arow + i*32] = v.z;
      At[kq*4+3][arow + i*32] = v.w;
    }
    #pragma unroll
    for (int i = 0; i < WI; i++){
      int k = kr + i * KRS;
      st4(&Wl[k][cq*4], ld4(W + (size_t)(kc + k) * N + cq*4));
    }
    __syncthreads();
    #pragma unroll 4
    for (int k = 0; k < KC; k++){
      float4 aLo = ld4(&At[k][r0]);
      float4 aHi = ld4(&At[k][r0 + 4]);
      float a[8] = {aLo.x,aLo.y,aLo.z,aLo.w,aHi.x,aHi.y,aHi.z,aHi.w};
      #pragma unroll
      for (int f = 0; f < NFRAG; f++){
        float4 b = ld4(&Wl[k][cg*4 + f*64]);
        #pragma unroll
        for (int i = 0; i < 8; i++){
          acc[i][f*4+0] = fmaf(a[i], b.x, acc[i][f*4+0]);
          acc[i][f*4+1] = fmaf(a[i], b.y, acc[i][f*4+1]);
          acc[i][f*4+2] = fmaf(a[i], b.z, acc[i][f*4+2]);
          acc[i][f*4+3] = fmaf(a[i], b.w, acc[i][f*4+3]);
        }
      }
    }
    __syncthreads();
  }
  #pragma unroll
  for (int f = 0; f < NFRAG; f++){
    float4 bb = ld4(bias + cg*4 + f*64);
    #pragma unroll
    for (int i = 0; i < 8; i++){
      float4 o;
      o.x = acc[i][f*4+0] + bb.x;  o.y = acc[i][f*4+1] + bb.y;
      o.z = acc[i][f*4+2] + bb.z;  o.w = acc[i][f*4+3] + bb.w;
      if (RELU){
        o.x = fmaxf(o.x, 0.f); o.y = fmaxf(o.y, 0.f);
        o.z = fmaxf(o.z, 0.f); o.w = fmaxf(o.w, 0.f);
      }
      st4(Out + (size_t)(rowbase + r0 + i) * N + cg*4 + f*64, o);
    }
  }
}

// ---------------- G4: dual GEMM (mu, logvar) + sample + kld + ||mu||^2 ----------------
__global__ __launch_bounds__(256) void g4_dual(const float* __restrict__ A,
    const float* __restrict__ Wm, const float* __restrict__ bm,
    const float* __restrict__ Wv, const float* __restrict__ bv,
    const float* __restrict__ epsIn,
    float* __restrict__ muO, float* __restrict__ sampleO,
    float* __restrict__ normMu2, float* __restrict__ kld_part){
  constexpr int KC = 32;
  __shared__ float At[KC][68];
  __shared__ float Wml[KC][CM];
  __shared__ float Wvl[KC][CM];
  __shared__ float nm[64];
  __shared__ float redbuf[4];
  const int tid = threadIdx.x;
  const int r0 = (tid >> 4) * 4;
  const int cg = tid & 15;
  const int arow = tid >> 3, kq = tid & 7;
  const int cq = tid & 31, kr = tid >> 5;
  const int rowbase = blockIdx.x * 64;
  if (tid < 64) nm[tid] = 0.f;

  float am[4][8], av[4][8];
  #pragma unroll
  for (int i = 0; i < 4; i++)
    #pragma unroll
    for (int j = 0; j < 8; j++){ am[i][j] = 0.f; av[i][j] = 0.f; }

  for (int kc = 0; kc < CM; kc += KC){
    #pragma unroll
    for (int i = 0; i < 2; i++){
      float4 v = ld4(A + (size_t)(rowbase + arow + i*32) * CM + kc + kq*4);
      At[kq*4+0][arow + i*32] = v.x;
      At[kq*4+1][arow + i*32] = v.y;
      At[kq*4+2][arow + i*32] = v.z;
      At[kq*4+3][arow + i*32] = v.w;
    }
    #pragma unroll
    for (int i = 0; i < 4; i++){
      int k = kr + i * 8;
      st4(&Wml[k][cq*4], ld4(Wm + (size_t)(kc + k) * CM + cq*4));
      st4(&Wvl[k][cq*4], ld4(Wv + (size_t)(kc + k) * CM + cq*4));
    }
    __syncthreads();
    #pragma unroll 4
    for (int k = 0; k < KC; k++){
      float4 a4 = ld4(&At[k][r0]);
      float a[4] = {a4.x, a4.y, a4.z, a4.w};
      #pragma unroll
      for (int f = 0; f < 2; f++){
        float4 bM = ld4(&Wml[k][cg*4 + f*64]);
        float4 bV = ld4(&Wvl[k][cg*4 + f*64]);
        #pragma unroll
        for (int i = 0; i < 4; i++){
          am[i][f*4+0] = fmaf(a[i], bM.x, am[i][f*4+0]);
          am[i][f*4+1] = fmaf(a[i], bM.y, am[i][f*4+1]);
          am[i][f*4+2] = fmaf(a[i], bM.z, am[i][f*4+2]);
          am[i][f*4+3] = fmaf(a[i], bM.w, am[i][f*4+3]);
          av[i][f*4+0] = fmaf(a[i], bV.x, av[i][f*4+0]);
          av[i][f*4+1] = fmaf(a[i], bV.y, av[i][f*4+1]);
          av[i][f*4+2] = fmaf(a[i], bV.z, av[i][f*4+2]);
          av[i][f*4+3] = fmaf(a[i], bV.w, av[i][f*4+3]);
        }
      }
    }
    __syncthreads();
  }

  float4 bm0 = ld4(bm + cg*4), bm1 = ld4(bm + cg*4 + 64);
  float4 bv0 = ld4(bv + cg*4), bv1 = ld4(bv + cg*4 + 64);
  float kl = 0.f;
  #pragma unroll
  for (int i = 0; i < 4; i++){
    int row = rowbase + r0 + i;
    float m2 = 0.f;
    #pragma unroll
    for (int f = 0; f < 2; f++){
      float4 ev = ld4(epsIn + (size_t)row * CM + cg*4 + f*64);
      float4 bmv = (f == 0) ? bm0 : bm1;
      float4 bvv = (f == 0) ? bv0 : bv1;
      float muv[4], lvv[4], sav[4];
      float evc[4] = {ev.x, ev.y, ev.z, ev.w};
      float bmc[4] = {bmv.x, bmv.y, bmv.z, bmv.w};
      float bvc[4] = {bvv.x, bvv.y, bvv.z, bvv.w};
      #pragma unroll
      for (int c = 0; c < 4; c++){
        muv[c] = am[i][f*4+c] + bmc[c];
        lvv[c] = av[i][f*4+c] + bvc[c];
        float s2 = expf(0.5f * lvv[c]);
        sav[c] = muv[c] + s2 * evc[c];
        kl += 1.f + lvv[c] - muv[c]*muv[c] - s2*s2;
        m2 += muv[c]*muv[c];
      }
      float4 mo = {muv[0], muv[1], muv[2], muv[3]};
      float4 so = {sav[0], sav[1], sav[2], sav[3]};
      st4(muO     + (size_t)row * CM + cg*4 + f*64, mo);
      st4(sampleO + (size_t)row * CM + cg*4 + f*64, so);
    }
    atomicAdd(&nm[r0 + i], m2);
  }
  float kw = wave_sum(kl);
  if ((tid & 63) == 0) redbuf[tid >> 6] = kw;
  __syncthreads();
  if (tid == 0) kld_part[blockIdx.x] = redbuf[0] + redbuf[1] + redbuf[2] + redbuf[3];
  if (tid < 64) normMu2[rowbase + tid] = nm[tid];
}

// ---------------- proto passes ----------------
// MODE 0: argmin over protos (sample) -> write output rows + commit partials
// MODE 1: rowsum of exp kernel (mu)   -> Srow
// MODE 2: approx-prob accumulation    -> per-block partials [NP]
template<int MODE>
__global__ __launch_bounds__(256) void proto_pass(const float* __restrict__ Amat,
    const float* __restrict__ protos, const float* __restrict__ normp2,
    const float* __restrict__ normMu2, const float* __restrict__ SrowIn,
    float* __restrict__ outA,
    const float* __restrict__ sampleG, const float* __restrict__ muG,
    float* __restrict__ commit_part){
  constexpr int BM = 64, PC = 512, KC = 32;
  __shared__ float At[KC][BM + 4];
  __shared__ float Pt[KC][PC + 4];
  __shared__ float np2l[PC];
  __shared__ int   bidxl[64];
  __shared__ float redbuf[4];
  __shared__ float approxl[(MODE == 2) ? NP : 4];

  const int tid = threadIdx.x;
  const int r0 = (tid >> 5) * 8;
  const int m4 = tid & 31;
  const int rowbase = blockIdx.x * BM;
  const int arow = tid >> 3, kq = tid & 7;

  float best[8]; int bidx[8];
  float sr[8], nmu[8], rs[8];
  #pragma unroll
  for (int i = 0; i < 8; i++){ best[i] = 3.4e38f; bidx[i] = 0; sr[i] = 0.f; nmu[i] = 0.f; rs[i] = 0.f; }
  if constexpr (MODE >= 1){
    #pragma unroll
    for (int i = 0; i < 8; i++) nmu[i] = normMu2[rowbase + r0 + i];
  }
  if constexpr (MODE == 2){
    #pragma unroll
    for (int i = 0; i < 8; i++) rs[i] = 1.0f / SrowIn[rowbase + r0 + i];
    for (int t = tid; t < NP; t += 256) approxl[t] = 0.f;
  }

  for (int pc = 0; pc < NP; pc += PC){
    float acc[8][16];
    #pragma unroll
    for (int i = 0; i < 8; i++)
      #pragma unroll
      for (int j = 0; j < 16; j++) acc[i][j] = 0.f;

    for (int kc = 0; kc < CM; kc += KC){
      #pragma unroll
      for (int i = 0; i < 2; i++){
        float4 v = ld4(Amat + (size_t)(rowbase + arow + i*32) * CM + kc + kq*4);
        At[kq*4+0][arow + i*32] = v.x;
        At[kq*4+1][arow + i*32] = v.y;
        At[kq*4+2][arow + i*32] = v.z;
        At[kq*4+3][arow + i*32] = v.w;
      }
      #pragma unroll
      for (int i = 0; i < 16; i++){
        int pp = arow + i * 32;
        float4 v = ld4(protos + (size_t)(pc + pp) * CM + kc + kq*4);
        Pt[kq*4+0][pp] = v.x;
        Pt[kq*4+1][pp] = v.y;
        Pt[kq*4+2][pp] = v.z;
        Pt[kq*4+3][pp] = v.w;
      }
      if (kc == 0){
        for (int t = tid; t < PC; t += 256) np2l[t] = normp2[pc + t];
      }
      __syncthreads();
      #pragma unroll 2
      for (int k = 0; k < KC; k++){
        float4 aLo = ld4(&At[k][r0]);
        float4 aHi = ld4(&At[k][r0 + 4]);
        float a[8] = {aLo.x,aLo.y,aLo.z,aLo.w,aHi.x,aHi.y,aHi.z,aHi.w};
        float p[16];
        #pragma unroll
        for (int j = 0; j < 4; j++){
          float4 pv = ld4(&Pt[k][m4*4 + j*128]);
          p[j*4+0] = pv.x; p[j*4+1] = pv.y; p[j*4+2] = pv.z; p[j*4+3] = pv.w;
        }
        #pragma unroll
        for (int i = 0; i < 8; i++)
          #pragma unroll
          for (int jj = 0; jj < 16; jj++)
            acc[i][jj] = fmaf(a[i], p[jj], acc[i][jj]);
      }
      __syncthreads();
    }

    #pragma unroll
    for (int j = 0; j < 4; j++){
      #pragma unroll
      for (int jj = 0; jj < 4; jj++){
        int pl = m4*4 + j*128 + jj;
        float npv = np2l[pl];
        int pg = pc + pl;
        if constexpr (MODE == 0){
          #pragma unroll
          for (int i = 0; i < 8; i++){
            float sc = npv - 2.f * acc[i][j*4+jj];
            if (sc < best[i]){ best[i] = sc; bidx[i] = pg; }
          }
        } else if constexpr (MODE == 1){
          #pragma unroll
          for (int i = 0; i < 8; i++)
            sr[i] += __expf(-0.125f * (nmu[i] + npv - 2.f * acc[i][j*4+jj]));
        } else {
          float t = 0.f;
          #pragma unroll
          for (int i = 0; i < 8; i++){
            float e = __expf(-0.125f * (nmu[i] + npv - 2.f * acc[i][j*4+jj]));
            t += (e + EPSV) * rs[i];
          }
          t += __shfl_xor(t, 32, 64);
          if ((tid & 63) < 32) atomicAdd(&approxl[pg], t);
        }
      }
    }
  }

  if constexpr (MODE == 0){
    #pragma unroll
    for (int m = 1; m < 32; m <<= 1){
      #pragma unroll
      for (int i = 0; i < 8; i++){
        float ob = __shfl_xor(best[i], m, 64);
        int   oi = __shfl_xor(bidx[i], m, 64);
        if (ob < best[i] || (ob == best[i] && oi < bidx[i])){ best[i] = ob; bidx[i] = oi; }
      }
    }
    if (m4 == 0){
      #pragma unroll
      for (int i = 0; i < 8; i++) bidxl[r0 + i] = bidx[i];
    }
    __syncthreads();
    const int row = tid >> 2, cp = tid & 3;
    const int rowg = rowbase + row;
    const int idx = bidxl[row];
    float cl = 0.f;
    #pragma unroll
    for (int c4 = 0; c4 < 8; c4++){
      int c = cp*32 + c4*4;
      float4 q = ld4(protos  + (size_t)idx  * CM + c);
      float4 s = ld4(sampleG + (size_t)rowg * CM + c);
      float4 m = ld4(muG     + (size_t)rowg * CM + c);
      float4 o;
      o.x = s.x + (q.x - s.x); o.y = s.y + (q.y - s.y);
      o.z = s.z + (q.z - s.z); o.w = s.w + (q.w - s.w);
      st4(outA + (size_t)rowg * CM + c, o);
      float dx = q.x - m.x, dy = q.y - m.y, dz = q.z - m.z, dw = q.w - m.w;
      cl += dx*dx + dy*dy + dz*dz + dw*dw;
    }
    float cw = wave_sum(cl);
    if ((tid & 63) == 0) redbuf[tid >> 6] = cw;
    __syncthreads();
    if (tid == 0) commit_part[blockIdx.x] = redbuf[0] + redbuf[1] + redbuf[2] + redbuf[3];
  } else if constexpr (MODE == 1){
    #pragma unroll
    for (int m = 1; m < 32; m <<= 1){
      #pragma unroll
      for (int i = 0; i < 8; i++) sr[i] += __shfl_xor(sr[i], m, 64);
    }
    if (m4 == 0){
      #pragma unroll
      for (int i = 0; i < 8; i++)
        outA[rowbase + r0 + i] = sr[i] + (float)NP * EPSV;
    }
  } else {
    __syncthreads();
    for (int t = tid; t < NP; t += 256)
      outA[(size_t)blockIdx.x * NP + t] = approxl[t];
  }
}

// ---------------- final reductions ----------------
__global__ __launch_bounds__(256) void k4a(const float* __restrict__ approx_part,
                                           float* __restrict__ ent_part){
  __shared__ float redbuf[4];
  const int tid = threadIdx.x;
  const int p = blockIdx.x * 256 + tid;
  float s = 0.f;
  for (int b = 0; b < 512; b++) s += approx_part[(size_t)b * NP + p];
  float a = s * (1.0f / 32768.0f);
  float t = -a * logf(a);
  float w = wave_sum(t);
  if ((tid & 63) == 0) redbuf[tid >> 6] = w;
  __syncthreads();
  if (tid == 0) ent_part[blockIdx.x] = redbuf[0] + redbuf[1] + redbuf[2] + redbuf[3];
}

__global__ __launch_bounds__(256) void k4b(const float* __restrict__ kld_part,
                                           const float* __restrict__ commit_part,
                                           const float* __restrict__ ent_part,
                                           float* __restrict__ outs){
  __shared__ float redbuf[8];
  const int tid = threadIdx.x;
  float k = 0.f, c = 0.f;
  for (int i = tid; i < 512; i += 256){ k += kld_part[i]; c += commit_part[i]; }
  float kw = wave_sum(k), cw = wave_sum(c);
  if ((tid & 63) == 0){ redbuf[tid >> 6] = kw; redbuf[4 + (tid >> 6)] = cw; }
  __syncthreads();
  if (tid == 0){
    float ks = redbuf[0] + redbuf[1] + redbuf[2] + redbuf[3];
    float cs = redbuf[4] + redbuf[5] + redbuf[6] + redbuf[7];
    float es = 0.f;
    for (int i = 0; i < 8; i++) es += ent_part[i];
    float kld = -0.5f * ks / 32768.0f;
    float m = cs / (32768.0f * 128.0f);
    float vq = BETA * m + m + ENT_W * es;
    outs[0] = kld + vq;   // KL_W = 1
    outs[1] = kld;
  }
}

extern "C" void kernel_launch(void* const* d_in, const int* in_sizes, int n_in,
                              void* d_out, int out_size, void* d_ws, size_t ws_size,
                              hipStream_t stream){
  const float* x      = (const float*)d_in[0];
  const float* epsIn  = (const float*)d_in[1];
  const float* W_emb  = (const float*)d_in[2];
  const float* b_emb  = (const float*)d_in[3];
  const float* W1     = (const float*)d_in[4];
  const float* b1     = (const float*)d_in[5];
  const float* W2     = (const float*)d_in[6];
  const float* b2     = (const float*)d_in[7];
  const float* W_mu   = (const float*)d_in[8];
  const float* b_mu   = (const float*)d_in[9];
  const float* W_var  = (const float*)d_in[10];
  const float* b_var  = (const float*)d_in[11];
  const float* protos = (const float*)d_in[12];
  float* out = (float*)d_out;
  float* ws = (float*)d_ws;

  const size_t M1 = 1024u * 1024u;
  float* h1     = ws;                 // [0, 2M)
  float* h2     = ws + 2*M1;          // [2M, 4M)
  float* h3     = ws + 4*M1;          // [4M, 8M)
  float* mu     = ws + 8*M1;          // [8M, 12M)
  float* sample = ws;                 // reuses h1+h2 (dead after G3)
  float* tail   = ws + 12*M1;
  float* normMu2     = tail;                  // 32768
  float* SrowBuf     = normMu2 + 32768;       // 32768
  float* normp2      = SrowBuf + 32768;       // 2048
  float* kld_part    = normp2 + 2048;         // 512
  float* commit_part = kld_part + 512;        // 512
  float* ent_part    = commit_part + 512;     // 16
  float* approx_part = ent_part + 16;         // 512*2048

  k_normp2<<<8, 256, 0, stream>>>(protos, normp2);
  mlp_gemm<512, 64, false><<<NB/128, 256, 0, stream>>>(x,  W_emb, b_emb, h1);
  mlp_gemm< 64, 64, true ><<<NB/128, 256, 0, stream>>>(h1, W1,    b1,    h2);
  mlp_gemm< 64,128, true ><<<NB/128, 256, 0, stream>>>(h2, W2,    b2,    h3);
  g4_dual<<<NB/64, 256, 0, stream>>>(h3, W_mu, b_mu, W_var, b_var, epsIn,
                                     mu, sample, normMu2, kld_part);
  proto_pass<0><<<NB/64, 256, 0, stream>>>(sample, protos, normp2, nullptr, nullptr,
                                           out, sample, mu, commit_part);
  proto_pass<1><<<NB/64, 256, 0, stream>>>(mu, protos, normp2, normMu2, nullptr,
                                           SrowBuf, nullptr, nullptr, nullptr);
  proto_pass<2><<<NB/64, 256, 0, stream>>>(mu, protos, normp2, normMu2, SrowBuf,
                                           approx_part, nullptr, nullptr, nullptr);
  k4a<<<8, 256, 0, stream>>>(approx_part, ent_part);
  k4b<<<1, 256, 0, stream>>>(kld_part, commit_part, ent_part, out + (size_t)NB * CM);
}

// Round 2
// 254.748 us; speedup vs baseline: 3.5705x; 3.5705x over previous
//
#include <hip/hip_runtime.h>
#include <cmath>

constexpr int NB   = 32768;   // batch rows
constexpr int IND  = 512;
constexpr int HIDD = 64;
constexpr int CM   = 128;     // COMM
constexpr int NP   = 2048;    // num protos
constexpr float BETA  = 0.25f;
constexpr float ENT_W = 0.1f;
constexpr float EPSV  = 1e-8f;

typedef __attribute__((ext_vector_type(8))) short short8v;   // 8 x bf16
typedef __attribute__((ext_vector_type(4))) float f32x4v;

__device__ __forceinline__ float4 ld4(const float* p){ return *reinterpret_cast<const float4*>(p); }
__device__ __forceinline__ void  st4(float* p, float4 v){ *reinterpret_cast<float4*>(p) = v; }

__device__ __forceinline__ unsigned short f2bf(float f){
  union { float f; unsigned u; } v; v.f = f;
  unsigned r = v.u + 0x7fffu + ((v.u >> 16) & 1u);   // RNE
  return (unsigned short)(r >> 16);
}

__device__ __forceinline__ float wave_sum(float v){
  #pragma unroll
  for (int m = 1; m < 64; m <<= 1) v += __shfl_xor(v, m, 64);
  return v;
}

// ---------------- K0: proto norms + bf16 copy ----------------
__global__ __launch_bounds__(256) void k_prep(const float* __restrict__ protos,
                                              float* __restrict__ normp2,
                                              unsigned short* __restrict__ pBF){
  int p = blockIdx.x * 256 + threadIdx.x;
  const float* row = protos + (size_t)p * CM;
  float s = 0.f;
  #pragma unroll
  for (int k = 0; k < CM; k += 4){
    float4 v = ld4(row + k);
    s += v.x*v.x + v.y*v.y + v.z*v.z + v.w*v.w;
    ushort4 u; u.x = f2bf(v.x); u.y = f2bf(v.y); u.z = f2bf(v.z); u.w = f2bf(v.w);
    *reinterpret_cast<ushort4*>(&pBF[(size_t)p * CM + k]) = u;
  }
  normp2[p] = s;
}

// ---------------- MLP tiled GEMM (fp32): Out = act(A@W + b) ----------------
template<int K, int N, bool RELU>
__global__ __launch_bounds__(256) void mlp_gemm(const float* __restrict__ A,
                                                const float* __restrict__ W,
                                                const float* __restrict__ bias,
                                                float* __restrict__ Out){
  constexpr int BM = 128, KC = 32;
  constexpr int TN = N / 16;
  constexpr int NFRAG = TN / 4;
  __shared__ float At[KC][BM + 4];
  __shared__ float Wl[KC][N];
  const int tid = threadIdx.x;
  const int r0 = (tid >> 4) * 8;
  const int cg = tid & 15;
  const int arow = tid >> 3, kq = tid & 7;
  const int cq = tid % (N / 4), kr = tid / (N / 4);
  constexpr int KRS = 256 / (N / 4);
  constexpr int WI  = (KC * N) / 1024;
  const int rowbase = blockIdx.x * BM;

  float acc[8][TN];
  #pragma unroll
  for (int i = 0; i < 8; i++)
    #pragma unroll
    for (int j = 0; j < TN; j++) acc[i][j] = 0.f;

  for (int kc = 0; kc < K; kc += KC){
    #pragma unroll
    for (int i = 0; i < 4; i++){
      float4 v = ld4(A + (size_t)(rowbase + arow + i*32) * K + kc + kq*4);
      At[kq*4+0][arow + i*32] = v.x;
      At[kq*4+1][arow + i*32] = v.y;
      At[kq*4+2][arow + i*32] = v.z;
      At[kq*4+3][arow + i*32] = v.w;
    }
    #pragma unroll
    for (int i = 0; i < WI; i++){
      int k = kr + i * KRS;
      st4(&Wl[k][cq*4], ld4(W + (size_t)(kc + k) * N + cq*4));
    }
    __syncthreads();
    #pragma unroll 4
    for (int k = 0; k < KC; k++){
      float4 aLo = ld4(&At[k][r0]);
      float4 aHi = ld4(&At[k][r0 + 4]);
      float a[8] = {aLo.x,aLo.y,aLo.z,aLo.w,aHi.x,aHi.y,aHi.z,aHi.w};
      #pragma unroll
      for (int f = 0; f < NFRAG; f++){
        float4 b = ld4(&Wl[k][cg*4 + f*64]);
        #pragma unroll
        for (int i = 0; i < 8; i++){
          acc[i][f*4+0] = fmaf(a[i], b.x, acc[i][f*4+0]);
          acc[i][f*4+1] = fmaf(a[i], b.y, acc[i][f*4+1]);
          acc[i][f*4+2] = fmaf(a[i], b.z, acc[i][f*4+2]);
          acc[i][f*4+3] = fmaf(a[i], b.w, acc[i][f*4+3]);
        }
      }
    }
    __syncthreads();
  }
  #pragma unroll
  for (int f = 0; f < NFRAG; f++){
    float4 bb = ld4(bias + cg*4 + f*64);
    #pragma unroll
    for (int i = 0; i < 8; i++){
      float4 o;
      o.x = acc[i][f*4+0] + bb.x;  o.y = acc[i][f*4+1] + bb.y;
      o.z = acc[i][f*4+2] + bb.z;  o.w = acc[i][f*4+3] + bb.w;
      if (RELU){
        o.x = fmaxf(o.x, 0.f); o.y = fmaxf(o.y, 0.f);
        o.z = fmaxf(o.z, 0.f); o.w = fmaxf(o.w, 0.f);
      }
      st4(Out + (size_t)(rowbase + r0 + i) * N + cg*4 + f*64, o);
    }
  }
}

// ---------------- G4: dual GEMM (mu, logvar) + sample + kld + ||mu||^2 + bf16 ----------------
__global__ __launch_bounds__(256) void g4_dual(const float* __restrict__ A,
    const float* __restrict__ Wm, const float* __restrict__ bm,
    const float* __restrict__ Wv, const float* __restrict__ bv,
    const float* __restrict__ epsIn,
    float* __restrict__ muO, unsigned short* __restrict__ muBFo,
    unsigned short* __restrict__ sBFo,
    float* __restrict__ normMu2, float* __restrict__ kld_part){
  constexpr int KC = 32;
  __shared__ float At[KC][68];
  __shared__ float Wml[KC][CM];
  __shared__ float Wvl[KC][CM];
  __shared__ float nm[64];
  __shared__ float redbuf[4];
  const int tid = threadIdx.x;
  const int r0 = (tid >> 4) * 4;
  const int cg = tid & 15;
  const int arow = tid >> 3, kq = tid & 7;
  const int cq = tid & 31, kr = tid >> 5;
  const int rowbase = blockIdx.x * 64;
  if (tid < 64) nm[tid] = 0.f;

  float am[4][8], av[4][8];
  #pragma unroll
  for (int i = 0; i < 4; i++)
    #pragma unroll
    for (int j = 0; j < 8; j++){ am[i][j] = 0.f; av[i][j] = 0.f; }

  for (int kc = 0; kc < CM; kc += KC){
    #pragma unroll
    for (int i = 0; i < 2; i++){
      float4 v = ld4(A + (size_t)(rowbase + arow + i*32) * CM + kc + kq*4);
      At[kq*4+0][arow + i*32] = v.x;
      At[kq*4+1][arow + i*32] = v.y;
      At[kq*4+2][arow + i*32] = v.z;
      At[kq*4+3][arow + i*32] = v.w;
    }
    #pragma unroll
    for (int i = 0; i < 4; i++){
      int k = kr + i * 8;
      st4(&Wml[k][cq*4], ld4(Wm + (size_t)(kc + k) * CM + cq*4));
      st4(&Wvl[k][cq*4], ld4(Wv + (size_t)(kc + k) * CM + cq*4));
    }
    __syncthreads();
    #pragma unroll 4
    for (int k = 0; k < KC; k++){
      float4 a4 = ld4(&At[k][r0]);
      float a[4] = {a4.x, a4.y, a4.z, a4.w};
      #pragma unroll
      for (int f = 0; f < 2; f++){
        float4 bM = ld4(&Wml[k][cg*4 + f*64]);
        float4 bV = ld4(&Wvl[k][cg*4 + f*64]);
        #pragma unroll
        for (int i = 0; i < 4; i++){
          am[i][f*4+0] = fmaf(a[i], bM.x, am[i][f*4+0]);
          am[i][f*4+1] = fmaf(a[i], bM.y, am[i][f*4+1]);
          am[i][f*4+2] = fmaf(a[i], bM.z, am[i][f*4+2]);
          am[i][f*4+3] = fmaf(a[i], bM.w, am[i][f*4+3]);
          av[i][f*4+0] = fmaf(a[i], bV.x, av[i][f*4+0]);
          av[i][f*4+1] = fmaf(a[i], bV.y, av[i][f*4+1]);
          av[i][f*4+2] = fmaf(a[i], bV.z, av[i][f*4+2]);
          av[i][f*4+3] = fmaf(a[i], bV.w, av[i][f*4+3]);
        }
      }
    }
    __syncthreads();
  }

  float4 bm0 = ld4(bm + cg*4), bm1 = ld4(bm + cg*4 + 64);
  float4 bv0 = ld4(bv + cg*4), bv1 = ld4(bv + cg*4 + 64);
  float kl = 0.f;
  #pragma unroll
  for (int i = 0; i < 4; i++){
    int row = rowbase + r0 + i;
    float m2 = 0.f;
    #pragma unroll
    for (int f = 0; f < 2; f++){
      float4 ev = ld4(epsIn + (size_t)row * CM + cg*4 + f*64);
      float4 bmv = (f == 0) ? bm0 : bm1;
      float4 bvv = (f == 0) ? bv0 : bv1;
      float muv[4], lvv[4], sav[4];
      float evc[4] = {ev.x, ev.y, ev.z, ev.w};
      float bmc[4] = {bmv.x, bmv.y, bmv.z, bmv.w};
      float bvc[4] = {bvv.x, bvv.y, bvv.z, bvv.w};
      #pragma unroll
      for (int c = 0; c < 4; c++){
        muv[c] = am[i][f*4+c] + bmc[c];
        lvv[c] = av[i][f*4+c] + bvc[c];
        float s2 = expf(0.5f * lvv[c]);
        sav[c] = muv[c] + s2 * evc[c];
        kl += 1.f + lvv[c] - muv[c]*muv[c] - s2*s2;
        m2 += muv[c]*muv[c];
      }
      float4 mo = {muv[0], muv[1], muv[2], muv[3]};
      st4(muO + (size_t)row * CM + cg*4 + f*64, mo);
      ushort4 ub; ub.x=f2bf(muv[0]); ub.y=f2bf(muv[1]); ub.z=f2bf(muv[2]); ub.w=f2bf(muv[3]);
      ushort4 us; us.x=f2bf(sav[0]); us.y=f2bf(sav[1]); us.z=f2bf(sav[2]); us.w=f2bf(sav[3]);
      *reinterpret_cast<ushort4*>(&muBFo[(size_t)row * CM + cg*4 + f*64]) = ub;
      *reinterpret_cast<ushort4*>(&sBFo [(size_t)row * CM + cg*4 + f*64]) = us;
    }
    atomicAdd(&nm[r0 + i], m2);
  }
  float kw = wave_sum(kl);
  if ((tid & 63) == 0) redbuf[tid >> 6] = kw;
  __syncthreads();
  if (tid == 0) kld_part[blockIdx.x] = redbuf[0] + redbuf[1] + redbuf[2] + redbuf[3];
  if (tid < 64) normMu2[rowbase + tid] = nm[tid];
}

// ---------------- Pass1 (MFMA): argmin(sample.p) + rowsum(exp on mu.p) fused ----------------
__global__ __launch_bounds__(256, 2) void proto_mfma1(
    const unsigned short* __restrict__ sBF, const unsigned short* __restrict__ mBF,
    const unsigned short* __restrict__ pBF, const float* __restrict__ normp2,
    const float* __restrict__ normMu2, const float* __restrict__ muF,
    const float* __restrict__ protosF, float* __restrict__ outA,
    float* __restrict__ SrowO, float* __restrict__ commit_part)
{
  __shared__ __align__(16) unsigned short As[64*CM];
  __shared__ __align__(16) unsigned short Am[64*CM];
  __shared__ __align__(16) unsigned short Ps[128*CM];
  __shared__ float srw[4][64];
  __shared__ float bestw[4][64];
  __shared__ int   bidxw[4][64];
  __shared__ float redbuf[4];

  const int tid = threadIdx.x;
  const int w = tid >> 6;
  const int l = tid & 63;
  const int lr = l >> 4, lc = l & 15;
  const int rowbase = blockIdx.x * 64;

  { // stage sample + mu A-tiles (64x128 bf16, XOR-swizzled)
    const int row = tid >> 2;
    #pragma unroll
    for (int i = 0; i < 4; i++){
      const int k = ((tid & 3) + i*4) * 8;
      const size_t gi = (size_t)(rowbase + row) * CM + k;
      const int li = (row*CM + k) ^ ((row & 7) << 3);
      *reinterpret_cast<short8v*>(&As[li]) = *reinterpret_cast<const short8v*>(&sBF[gi]);
      *reinterpret_cast<short8v*>(&Am[li]) = *reinterpret_cast<const short8v*>(&mBF[gi]);
    }
  }

  float nmu[16];
  #pragma unroll
  for (int mt = 0; mt < 4; mt++)
    #pragma unroll
    for (int r = 0; r < 4; r++)
      nmu[mt*4+r] = normMu2[rowbase + mt*16 + lr*4 + r];

  float best[16]; int bidx[16]; float sr[16];
  #pragma unroll
  for (int i = 0; i < 16; i++){ best[i] = 3.4e38f; bidx[i] = 0; sr[i] = 0.f; }

  for (int pc = 0; pc < NP; pc += 128){
    __syncthreads();
    { // stage 128-proto chunk
      const int prow = tid >> 1;
      #pragma unroll
      for (int i = 0; i < 8; i++){
        const int k = ((tid & 1) + i*2) * 8;
        const int li = (prow*CM + k) ^ ((prow & 7) << 3);
        *reinterpret_cast<short8v*>(&Ps[li]) =
            *reinterpret_cast<const short8v*>(&pBF[(size_t)(pc + prow) * CM + k]);
      }
    }
    __syncthreads();

    f32x4v acc_s[4][2], acc_m[4][2];
    #pragma unroll
    for (int mt = 0; mt < 4; mt++)
      #pragma unroll
      for (int nt = 0; nt < 2; nt++){
        acc_s[mt][nt] = (f32x4v){0.f,0.f,0.f,0.f};
        acc_m[mt][nt] = (f32x4v){0.f,0.f,0.f,0.f};
      }
    #pragma unroll
    for (int ks = 0; ks < 4; ks++){
      short8v af[4], mf[4], pf[2];
      #pragma unroll
      for (int mt = 0; mt < 4; mt++){
        const int row = mt*16 + lc;
        const int idx = (row*CM + ks*32 + lr*8) ^ ((row & 7) << 3);
        af[mt] = *reinterpret_cast<const short8v*>(&As[idx]);
        mf[mt] = *reinterpret_cast<const short8v*>(&Am[idx]);
      }
      #pragma unroll
      for (int nt = 0; nt < 2; nt++){
        const int prow = w*32 + nt*16 + lc;
        const int idx = (prow*CM + ks*32 + lr*8) ^ ((prow & 7) << 3);
        pf[nt] = *reinterpret_cast<const short8v*>(&Ps[idx]);
      }
      #pragma unroll
      for (int mt = 0; mt < 4; mt++)
        #pragma unroll
        for (int nt = 0; nt < 2; nt++){
          acc_s[mt][nt] = __builtin_amdgcn_mfma_f32_16x16x32_bf16(af[mt], pf[nt], acc_s[mt][nt], 0, 0, 0);
          acc_m[mt][nt] = __builtin_amdgcn_mfma_f32_16x16x32_bf16(mf[mt], pf[nt], acc_m[mt][nt], 0, 0, 0);
        }
    }
    #pragma unroll
    for (int nt = 0; nt < 2; nt++){
      const int pg = pc + w*32 + nt*16 + lc;
      const float npv = normp2[pg];
      #pragma unroll
      for (int mt = 0; mt < 4; mt++)
        #pragma unroll
        for (int r = 0; r < 4; r++){
          const float sc = npv - 2.f * acc_s[mt][nt][r];
          if (sc < best[mt*4+r]){ best[mt*4+r] = sc; bidx[mt*4+r] = pg; }
          sr[mt*4+r] += __expf(-0.125f * (nmu[mt*4+r] + npv - 2.f * acc_m[mt][nt][r]));
        }
    }
  }

  #pragma unroll
  for (int m = 1; m < 16; m <<= 1){
    #pragma unroll
    for (int i = 0; i < 16; i++){
      const float ob = __shfl_xor(best[i], m, 64);
      const int   oi = __shfl_xor(bidx[i], m, 64);
      if (ob < best[i] || (ob == best[i] && oi < bidx[i])){ best[i] = ob; bidx[i] = oi; }
      sr[i] += __shfl_xor(sr[i], m, 64);
    }
  }
  if (lc == 0){
    #pragma unroll
    for (int mt = 0; mt < 4; mt++)
      #pragma unroll
      for (int r = 0; r < 4; r++){
        const int row = mt*16 + lr*4 + r;
        bestw[w][row] = best[mt*4+r];
        bidxw[w][row] = bidx[mt*4+r];
        srw[w][row]   = sr[mt*4+r];
      }
  }
  __syncthreads();
  if (tid < 64){
    float b = bestw[0][tid]; int bi = bidxw[0][tid];
    float s = srw[0][tid];
    #pragma unroll
    for (int ww = 1; ww < 4; ww++){
      const float ob = bestw[ww][tid]; const int oi = bidxw[ww][tid];
      if (ob < b || (ob == b && oi < bi)){ b = ob; bi = oi; }
      s += srw[ww][tid];
    }
    bidxw[0][tid] = bi;
    SrowO[rowbase + tid] = s + (float)NP * EPSV;
  }
  __syncthreads();
  // out rows = protos[idx] (fp32) + commitment partial
  const int row = tid >> 2, cp = tid & 3;
  const int rowg = rowbase + row;
  const int idx = bidxw[0][row];
  float cl = 0.f;
  #pragma unroll
  for (int c4 = 0; c4 < 8; c4++){
    const int c = cp*32 + c4*4;
    float4 q = ld4(protosF + (size_t)idx  * CM + c);
    float4 m = ld4(muF     + (size_t)rowg * CM + c);
    st4(outA + (size_t)rowg * CM + c, q);
    const float dx=q.x-m.x, dy=q.y-m.y, dz=q.z-m.z, dw=q.w-m.w;
    cl += dx*dx + dy*dy + dz*dz + dw*dw;
  }
  const float cw = wave_sum(cl);
  if ((tid & 63) == 0) redbuf[tid >> 6] = cw;
  __syncthreads();
  if (tid == 0) commit_part[blockIdx.x] = redbuf[0]+redbuf[1]+redbuf[2]+redbuf[3];
}

// ---------------- Pass2 (MFMA): approx-prob accumulation ----------------
__global__ __launch_bounds__(256, 2) void proto_mfma2(
    const unsigned short* __restrict__ mBF, const unsigned short* __restrict__ pBF,
    const float* __restrict__ normp2, const float* __restrict__ normMu2,
    const float* __restrict__ SrowI, float* __restrict__ approx_part)
{
  __shared__ __align__(16) unsigned short Am[64*CM];
  __shared__ __align__(16) unsigned short Ps[128*CM];

  const int tid = threadIdx.x;
  const int w = tid >> 6;
  const int l = tid & 63;
  const int lr = l >> 4, lc = l & 15;
  const int rowbase = blockIdx.x * 64;

  {
    const int row = tid >> 2;
    #pragma unroll
    for (int i = 0; i < 4; i++){
      const int k = ((tid & 3) + i*4) * 8;
      const int li = (row*CM + k) ^ ((row & 7) << 3);
      *reinterpret_cast<short8v*>(&Am[li]) =
          *reinterpret_cast<const short8v*>(&mBF[(size_t)(rowbase + row) * CM + k]);
    }
  }

  float nmu[16], rs[16];
  #pragma unroll
  for (int mt = 0; mt < 4; mt++)
    #pragma unroll
    for (int r = 0; r < 4; r++){
      const int row = rowbase + mt*16 + lr*4 + r;
      nmu[mt*4+r] = normMu2[row];
      rs[mt*4+r]  = 1.0f / SrowI[row];
    }

  for (int pc = 0; pc < NP; pc += 128){
    __syncthreads();
    {
      const int prow = tid >> 1;
      #pragma unroll
      for (int i = 0; i < 8; i++){
        const int k = ((tid & 1) + i*2) * 8;
        const int li = (prow*CM + k) ^ ((prow & 7) << 3);
        *reinterpret_cast<short8v*>(&Ps[li]) =
            *reinterpret_cast<const short8v*>(&pBF[(size_t)(pc + prow) * CM + k]);
      }
    }
    __syncthreads();

    f32x4v acc[4][2];
    #pragma unroll
    for (int mt = 0; mt < 4; mt++)
      #pragma unroll
      for (int nt = 0; nt < 2; nt++) acc[mt][nt] = (f32x4v){0.f,0.f,0.f,0.f};
    #pragma unroll
    for (int ks = 0; ks < 4; ks++){
      short8v mf[4], pf[2];
      #pragma unroll
      for (int mt = 0; mt < 4; mt++){
        const int row = mt*16 + lc;
        const int idx = (row*CM + ks*32 + lr*8) ^ ((row & 7) << 3);
        mf[mt] = *reinterpret_cast<const short8v*>(&Am[idx]);
      }
      #pragma unroll
      for (int nt = 0; nt < 2; nt++){
        const int prow = w*32 + nt*16 + lc;
        const int idx = (prow*CM + ks*32 + lr*8) ^ ((prow & 7) << 3);
        pf[nt] = *reinterpret_cast<const short8v*>(&Ps[idx]);
      }
      #pragma unroll
      for (int mt = 0; mt < 4; mt++)
        #pragma unroll
        for (int nt = 0; nt < 2; nt++)
          acc[mt][nt] = __builtin_amdgcn_mfma_f32_16x16x32_bf16(mf[mt], pf[nt], acc[mt][nt], 0, 0, 0);
    }
    #pragma unroll
    for (int nt = 0; nt < 2; nt++){
      const int pg = pc + w*32 + nt*16 + lc;
      const float npv = normp2[pg];
      float cs = 0.f;
      #pragma unroll
      for (int mt = 0; mt < 4; mt++)
        #pragma unroll
        for (int r = 0; r < 4; r++){
          const float e = __expf(-0.125f * (nmu[mt*4+r] + npv - 2.f * acc[mt][nt][r])) + EPSV;
          cs += e * rs[mt*4+r];
        }
      cs += __shfl_xor(cs, 16, 64);
      cs += __shfl_xor(cs, 32, 64);
      if (l < 16) approx_part[(size_t)blockIdx.x * NP + pg] = cs;
    }
  }
}

// ---------------- final reductions ----------------
__global__ __launch_bounds__(256) void k4a(const float* __restrict__ approx_part,
                                           float* __restrict__ ent_part){
  __shared__ float redbuf[4];
  const int tid = threadIdx.x;
  const int p = blockIdx.x * 256 + tid;
  float s = 0.f;
  for (int b = 0; b < 512; b++) s += approx_part[(size_t)b * NP + p];
  float a = s * (1.0f / 32768.0f);
  float t = -a * logf(a);
  float w = wave_sum(t);
  if ((tid & 63) == 0) redbuf[tid >> 6] = w;
  __syncthreads();
  if (tid == 0) ent_part[blockIdx.x] = redbuf[0] + redbuf[1] + redbuf[2] + redbuf[3];
}

__global__ __launch_bounds__(256) void k4b(const float* __restrict__ kld_part,
                                           const float* __restrict__ commit_part,
                                           const float* __restrict__ ent_part,
                                           float* __restrict__ outs){
  __shared__ float redbuf[8];
  const int tid = threadIdx.x;
  float k = 0.f, c = 0.f;
  for (int i = tid; i < 512; i += 256){ k += kld_part[i]; c += commit_part[i]; }
  float kw = wave_sum(k), cw = wave_sum(c);
  if ((tid & 63) == 0){ redbuf[tid >> 6] = kw; redbuf[4 + (tid >> 6)] = cw; }
  __syncthreads();
  if (tid == 0){
    float ks = redbuf[0] + redbuf[1] + redbuf[2] + redbuf[3];
    float cs = redbuf[4] + redbuf[5] + redbuf[6] + redbuf[7];
    float es = 0.f;
    for (int i = 0; i < 8; i++) es += ent_part[i];
    float kld = -0.5f * ks / 32768.0f;
    float m = cs / (32768.0f * 128.0f);
    float vq = BETA * m + m + ENT_W * es;
    outs[0] = kld + vq;   // KL_W = 1
    outs[1] = kld;
  }
}

extern "C" void kernel_launch(void* const* d_in, const int* in_sizes, int n_in,
                              void* d_out, int out_size, void* d_ws, size_t ws_size,
                              hipStream_t stream){
  const float* x      = (const float*)d_in[0];
  const float* epsIn  = (const float*)d_in[1];
  const float* W_emb  = (const float*)d_in[2];
  const float* b_emb  = (const float*)d_in[3];
  const float* W1     = (const float*)d_in[4];
  const float* b1     = (const float*)d_in[5];
  const float* W2     = (const float*)d_in[6];
  const float* b2     = (const float*)d_in[7];
  const float* W_mu   = (const float*)d_in[8];
  const float* b_mu   = (const float*)d_in[9];
  const float* W_var  = (const float*)d_in[10];
  const float* b_var  = (const float*)d_in[11];
  const float* protos = (const float*)d_in[12];
  float* out = (float*)d_out;
  float* ws = (float*)d_ws;

  const size_t M1 = 1024u * 1024u;
  float* h1 = ws;                       // [0, 2M) floats
  float* h2 = ws + 2*M1;                // [2M, 4M)
  float* h3 = ws + 4*M1;                // [4M, 8M)  (16MB)
  float* mu = ws + 8*M1;                // [8M, 12M)
  unsigned short* sBF = (unsigned short*)ws;            // overlays h1 (dead after mlp#2)
  unsigned short* mBF = (unsigned short*)(ws + 2*M1);   // overlays h2 (dead after mlp#3)
  float* approx_part = ws + 4*M1;       // overlays h3 (dead after g4_dual)
  float* tail = ws + 12*M1;
  float* normMu2     = tail;                  // 32768
  float* SrowBuf     = normMu2 + 32768;       // 32768
  float* normp2      = SrowBuf + 32768;       // 2048
  float* kld_part    = normp2 + 2048;         // 512
  float* commit_part = kld_part + 512;        // 512
  float* ent_part    = commit_part + 512;     // 16
  unsigned short* pBF = (unsigned short*)(ent_part + 16);  // 2048*128 ushort

  k_prep<<<8, 256, 0, stream>>>(protos, normp2, pBF);
  mlp_gemm<512, 64, false><<<NB/128, 256, 0, stream>>>(x,  W_emb, b_emb, h1);
  mlp_gemm< 64, 64, true ><<<NB/128, 256, 0, stream>>>(h1, W1,    b1,    h2);
  mlp_gemm< 64,128, true ><<<NB/128, 256, 0, stream>>>(h2, W2,    b2,    h3);
  g4_dual<<<NB/64, 256, 0, stream>>>(h3, W_mu, b_mu, W_var, b_var, epsIn,
                                     mu, mBF, sBF, normMu2, kld_part);
  proto_mfma1<<<NB/64, 256, 0, stream>>>(sBF, mBF, pBF, normp2, normMu2,
                                         mu, protos, out, SrowBuf, commit_part);
  proto_mfma2<<<NB/64, 256, 0, stream>>>(mBF, pBF, normp2, normMu2, SrowBuf,
                                         approx_part);
  k4a<<<8, 256, 0, stream>>>(approx_part, ent_part);
  k4b<<<1, 256, 0, stream>>>(kld_part, commit_part, ent_part, out + (size_t)NB * CM);
}